// Round 1
// baseline (225.708 us; speedup 1.0000x reference)
//
#include <hip/hip_runtime.h>
#include <hip/hip_bf16.h>
#include <math.h>

// B=8, L=32, H=1024, N=32
// ws layout (floats):
//   node   [8*32*32*32] @ 0
//   chart  [8*32*32*32] @ 262144
//   span   [8*32*32]    @ 524288
//   posn   [8*32*32]    @ 532480
//   R      [32*32*32]   @ 540672  (exp of masked rule_scores)
//   Epu    [32*32]      @ 573440  (exp of masked pos_unary)

__global__ __launch_bounds__(256) void k_node_span(
    const float* __restrict__ ph, const float* __restrict__ Wn,
    const float* __restrict__ bn, const float* __restrict__ Ws,
    const float* __restrict__ bs, float* __restrict__ node,
    float* __restrict__ span) {
  __shared__ float A[32][129];   // +1 pad: banks (r+h)%32 distinct across r
  __shared__ float Wl[128][32];
  __shared__ float Wsl[128];
  int t = threadIdx.x;
  int row0 = blockIdx.x * 32;
  int r = t >> 3, c0 = t & 7;
  float acc0 = 0.f, acc1 = 0.f, acc2 = 0.f, acc3 = 0.f, sp = 0.f;
  for (int hc = 0; hc < 8; ++hc) {
#pragma unroll
    for (int k = 0; k < 16; ++k) {            // stage A chunk (coalesced)
      int f = t + 256 * k;
      int rr = f >> 7, hh = f & 127;
      A[rr][hh] = ph[(row0 + rr) * 1024 + hc * 128 + hh];
    }
#pragma unroll
    for (int k = 0; k < 16; ++k) {            // stage W chunk (coalesced)
      int f = t + 256 * k;
      int hh = f >> 5, cc = f & 31;
      Wl[hh][cc] = Wn[(hc * 128 + hh) * 32 + cc];
    }
    if (t < 128) Wsl[t] = Ws[hc * 128 + t];
    __syncthreads();
#pragma unroll 4
    for (int h = 0; h < 128; ++h) {
      float a = A[r][h];
      acc0 += a * Wl[h][c0];
      acc1 += a * Wl[h][c0 + 8];
      acc2 += a * Wl[h][c0 + 16];
      acc3 += a * Wl[h][c0 + 24];
    }
#pragma unroll
    for (int hh = 0; hh < 16; ++hh) {         // span partial: 16 h's per thread
      int h = c0 * 16 + hh;
      sp += A[r][h] * Wsl[h];
    }
    __syncthreads();
  }
  int row = row0 + r;
  node[row * 32 + c0]      = acc0 + bn[c0];
  node[row * 32 + c0 + 8]  = acc1 + bn[c0 + 8];
  node[row * 32 + c0 + 16] = acc2 + bn[c0 + 16];
  node[row * 32 + c0 + 24] = acc3 + bn[c0 + 24];
  sp += __shfl_down(sp, 4, 8);
  sp += __shfl_down(sp, 2, 8);
  sp += __shfl_down(sp, 1, 8);
  if (c0 == 0) span[row] = sp + bs[0];
}

__global__ __launch_bounds__(256) void k_posnode(
    const float* __restrict__ sh, const float* __restrict__ Wp,
    const float* __restrict__ bp, const float* __restrict__ pmask,
    float* __restrict__ posn) {
  __shared__ float rowl[1024];
  __shared__ float part[8][33];
  int t = threadIdx.x;
  int row = blockIdx.x;
#pragma unroll
  for (int k = 0; k < 4; ++k) rowl[t + 256 * k] = sh[row * 1024 + t + 256 * k];
  __syncthreads();
  int c = t & 31, seg = t >> 5;
  float p = 0.f;
  for (int hh = 0; hh < 128; ++hh) {
    int h = seg * 128 + hh;
    p += rowl[h] * Wp[h * 32 + c];
  }
  part[seg][c] = p;
  __syncthreads();
  if (t < 32) {
    float s = 0.f;
#pragma unroll
    for (int k = 0; k < 8; ++k) s += part[k][t];
    posn[row * 32 + t] = s + bp[t] + (pmask[t] - 1.0f) * 1e10f;
  }
}

__global__ void k_expprep(const float* __restrict__ rs, const float* __restrict__ rm,
                          const float* __restrict__ pu, const float* __restrict__ pum,
                          float* __restrict__ R, float* __restrict__ Epu) {
  int idx = blockIdx.x * 256 + threadIdx.x;
  if (idx < 32768) R[idx] = expf(rs[idx] + (rm[idx] - 1.0f) * 1e10f);
  if (idx < 1024)  Epu[idx] = expf(pu[idx] + (pum[idx] - 1.0f) * 1e15f);
}

// chart diag: chart[b,l,l,p] = node_diag[p] + mq + log(sum_q Epu[p][q]*exp(posn[q]-mq))
__global__ void k_diag(const float* __restrict__ posn, const float* __restrict__ Epu,
                       const float* __restrict__ node, float* __restrict__ chart) {
  int lane = threadIdx.x;            // 64 threads, 2 cells per block
  int p = lane & 31;
  int row = blockIdx.x * 2 + (lane >> 5);   // b*32 + l
  float v = posn[row * 32 + p];
  float mq = v;
#pragma unroll
  for (int m = 16; m >= 1; m >>= 1) mq = fmaxf(mq, __shfl_xor(mq, m, 32));
  float pe = expf(v - mq);
  float sum = 0.f;
#pragma unroll
  for (int q = 0; q < 32; ++q) {
    float peq = __shfl(pe, q, 32);
    sum += Epu[p * 32 + q] * peq;
  }
  int l = row & 31;
  int diag = (row * 32 + l) * 32 + p;
  chart[diag] = node[diag] + mq + logf(sum);
}

// one block per chart cell (b, t, t+i); 1024 threads
__global__ __launch_bounds__(1024) void k_stage(
    const float* __restrict__ node, const float* __restrict__ span,
    const float* __restrict__ R, float* __restrict__ chart, int i, int nT) {
  __shared__ float EL[31][32];
  __shared__ float ER[31][32];
  __shared__ float gam[32];
  __shared__ float G_s;
  __shared__ float S_lds[1024];
  int tid = threadIdx.x;
  int cell = blockIdx.x;
  int b = cell / nT, t0 = cell % nT;
  int bt = b * 32;
  bool act = tid < i * 32;
  int j = tid >> 5, p = tid & 31;
  float left = 0.f, right = 0.f, beta = 0.f;
  if (act) {
    int li = ((bt + t0) * 32 + (t0 + j)) * 32 + p;
    left = chart[li] + node[li];
    int ri = ((bt + t0 + j + 1) * 32 + (t0 + i)) * 32 + p;
    right = chart[ri] + node[ri];
    float alpha = left;
    beta = right;
#pragma unroll
    for (int m = 16; m >= 1; m >>= 1) {
      alpha = fmaxf(alpha, __shfl_xor(alpha, m, 32));
      beta  = fmaxf(beta,  __shfl_xor(beta,  m, 32));
    }
    if (p == 0) gam[j] = alpha + beta;
  }
  __syncthreads();
  if (tid == 0) {
    float G = -INFINITY;
    for (int jj = 0; jj < i; ++jj) G = fmaxf(G, gam[jj]);
    G_s = G;
  }
  __syncthreads();
  float G = G_s;
  if (act) {
    EL[j][p] = expf(left + beta - G);   // = exp(left - a[j] + gamma[j] - G)
    ER[j][p] = expf(right - beta);
  }
  __syncthreads();
  {  // S[p,q] = sum_j EL[j][p]*ER[j][q]
    int pp = tid >> 5, qq = tid & 31;
    float S = 0.f;
    for (int jj = 0; jj < i; ++jj) S += EL[jj][pp] * ER[jj][qq];
    S_lds[tid] = S;
  }
  __syncthreads();
  {  // inner[a] = G + log(sum_pq R[a][pq]*S[pq])
    int a = tid >> 5, c = tid & 31;
    const float* Ra = R + a * 1024;
    float part = 0.f;
#pragma unroll 8
    for (int k = 0; k < 32; ++k) part += Ra[k * 32 + c] * S_lds[k * 32 + c];
#pragma unroll
    for (int m = 16; m >= 1; m >>= 1) part += __shfl_xor(part, m, 32);
    if (c == 0) {
      int oi = ((bt + t0) * 32 + (t0 + i)) * 32 + a;
      chart[oi] = G + logf(part) + node[oi] + span[(bt + t0) * 32 + t0 + i];
    }
  }
}

__global__ void k_logits(const float* __restrict__ chart, const int* __restrict__ sm,
                         const float* __restrict__ rootm, float* __restrict__ out) {
  int t = threadIdx.x;          // 256 threads
  int b = t >> 5, a = t & 31;
  int len = 0;
#pragma unroll
  for (int l = 0; l < 32; ++l) len += sm[b * 32 + l];
  int ci = ((b * 32 + 0) * 32 + (len - 1)) * 32 + a;
  out[b * 32 + a] = chart[ci] + (rootm[a] - 1.0f) * 1e10f;
}

extern "C" void kernel_launch(void* const* d_in, const int* in_sizes, int n_in,
                              void* d_out, int out_size, void* d_ws, size_t ws_size,
                              hipStream_t stream) {
  const float* ph    = (const float*)d_in[0];   // phrase_hiddens (8,32,32,1024)
  const float* sh    = (const float*)d_in[1];   // seq_hiddens (8,32,1024)
  const int*   sm    = (const int*)  d_in[2];   // seq_masks (8,32)
  const float* Wp    = (const float*)d_in[3];   // W_posnode (1024,32)
  const float* bp    = (const float*)d_in[4];   // b_posnode (32)
  const float* Wn    = (const float*)d_in[5];   // W_node (1024,32)
  const float* bn    = (const float*)d_in[6];   // b_node (32)
  const float* Ws    = (const float*)d_in[7];   // W_span (1024)
  const float* bs    = (const float*)d_in[8];   // b_span (1)
  const float* rs    = (const float*)d_in[9];   // rule_scores (32,32,32)
  const float* pu    = (const float*)d_in[10];  // pos_unary_rule_scores (32,32)
  const float* rootm = (const float*)d_in[11];  // root_mask (32)
  const float* pm    = (const float*)d_in[12];  // posnode_mask (32)
  const float* rm    = (const float*)d_in[13];  // rule_mask (32,32,32)
  const float* pum   = (const float*)d_in[14];  // pos_unary_rule_mask (32,32)
  float* out = (float*)d_out;

  float* ws    = (float*)d_ws;
  float* node  = ws;
  float* chart = ws + 262144;
  float* span  = ws + 524288;
  float* posn  = ws + 532480;
  float* R     = ws + 540672;
  float* Epu   = ws + 573440;

  k_node_span<<<256, 256, 0, stream>>>(ph, Wn, bn, Ws, bs, node, span);
  k_posnode<<<256, 256, 0, stream>>>(sh, Wp, bp, pm, posn);
  k_expprep<<<128, 256, 0, stream>>>(rs, rm, pu, pum, R, Epu);
  k_diag<<<128, 64, 0, stream>>>(posn, Epu, node, chart);
  for (int i = 1; i < 32; ++i) {
    int nT = 32 - i;
    k_stage<<<8 * nT, 1024, 0, stream>>>(node, span, R, chart, i, nT);
  }
  k_logits<<<1, 256, 0, stream>>>(chart, sm, rootm, out);
}

// Round 2
// 189.458 us; speedup vs baseline: 1.1913x; 1.1913x over previous
//
#include <hip/hip_runtime.h>
#include <math.h>

// B=8, L=32, H=1024, N=32
// ws layout (floats):
#define NODE_OFF   0          // 8192*32
#define CHART_OFF  262144     // 8192*32
#define CN_OFF     524288     // 8192*32  (chart + node)
#define SPAN_OFF   786432     // 8192
#define D_OFF      794624     // 256*32   (diag lse part)
#define R_OFF      802816     // 32*32*32 (exp masked rules)
#define PART_OFF   835584     // 4*262144 (split-K node partials)
#define PARTS_OFF  1884160    // 4*8192   (split-K span partials)

// blocks 0..255: posnode row GEMM + D row; blocks 256..383: R = exp(masked rules)
__global__ __launch_bounds__(256) void k_prep(
    const float* __restrict__ sh, const float* __restrict__ Wp,
    const float* __restrict__ bp, const float* __restrict__ pmask,
    const float* __restrict__ pu, const float* __restrict__ pum,
    const float* __restrict__ rs, const float* __restrict__ rm,
    float* __restrict__ D, float* __restrict__ R) {
  int t = threadIdx.x;
  int bid = blockIdx.x;
  if (bid >= 256) {
    int idx = ((bid - 256) << 8) + t;
    R[idx] = __expf(rs[idx] + (rm[idx] - 1.0f) * 1e10f);
    return;
  }
  __shared__ float rowl[1024];
  __shared__ float partl[8][33];
  __shared__ float posn[32];
#pragma unroll
  for (int k = 0; k < 4; ++k) rowl[t + 256 * k] = sh[bid * 1024 + t + 256 * k];
  __syncthreads();
  int c = t & 31, seg = t >> 5;
  float pacc = 0.f;
  for (int hh = 0; hh < 128; ++hh)
    pacc += rowl[seg * 128 + hh] * Wp[(seg * 128 + hh) * 32 + c];
  partl[seg][c] = pacc;
  __syncthreads();
  if (t < 32) {
    float s = 0.f;
#pragma unroll
    for (int k = 0; k < 8; ++k) s += partl[k][t];
    posn[t] = s + bp[t] + (pmask[t] - 1.0f) * 1e10f;
  }
  __syncthreads();
  if (t < 32) {
    float mq = posn[t];
#pragma unroll
    for (int m = 16; m >= 1; m >>= 1) mq = fmaxf(mq, __shfl_xor(mq, m, 32));
    float sum = 0.f;
#pragma unroll 8
    for (int q = 0; q < 32; ++q)
      sum += __expf(pu[t * 32 + q] + (pum[t * 32 + q] - 1.0f) * 1e15f + posn[q] - mq);
    D[bid * 32 + t] = mq + __logf(sum);
  }
}

// split-K node GEMM: grid 512 = 128 rowgroups(64 rows) x 4 k-slices(256 h).
// thread tile 2 rows x 4 cols (float4 W).
__global__ __launch_bounds__(256) void k_node_main(
    const float* __restrict__ ph, const float* __restrict__ Wn,
    const float* __restrict__ Ws, float* __restrict__ part,
    float* __restrict__ partS) {
  __shared__ float A[64][132];
  __shared__ float Wl[128][32];
  __shared__ float Wsl[128];
  int t = threadIdx.x;
  int rg = blockIdx.x >> 2;
  int s = blockIdx.x & 3;
  int row0 = rg * 64;
  int h0 = s * 256;
  int tr = t >> 3, tc = t & 7;
  int r0 = tr * 2;
  int c = tc * 4;
  float acc[8] = {0.f, 0.f, 0.f, 0.f, 0.f, 0.f, 0.f, 0.f};
  float sp0 = 0.f, sp1 = 0.f;
  for (int hc = 0; hc < 2; ++hc) {
    int hb = h0 + hc * 128;
#pragma unroll
    for (int k = 0; k < 32; ++k) {            // stage A 64x128 (coalesced)
      int f = t + 256 * k;
      int rr = f >> 7, hh = f & 127;
      A[rr][hh] = ph[(row0 + rr) * 1024 + hb + hh];
    }
#pragma unroll
    for (int k = 0; k < 16; ++k) {            // stage W 128x32 (coalesced)
      int f = t + 256 * k;
      int hh = f >> 5, cc = f & 31;
      Wl[hh][cc] = Wn[(hb + hh) * 32 + cc];
    }
    if (t < 128) Wsl[t] = Ws[hb + t];
    __syncthreads();
#pragma unroll 2
    for (int h = 0; h < 128; ++h) {
      float a0 = A[r0][h], a1 = A[r0 + 1][h];
      float4 w = *(const float4*)&Wl[h][c];
      acc[0] += a0 * w.x; acc[1] += a0 * w.y; acc[2] += a0 * w.z; acc[3] += a0 * w.w;
      acc[4] += a1 * w.x; acc[5] += a1 * w.y; acc[6] += a1 * w.z; acc[7] += a1 * w.w;
      if (tc == 0) { float wv = Wsl[h]; sp0 += a0 * wv; sp1 += a1 * wv; }
    }
    __syncthreads();
  }
  int row = row0 + r0;
  float* po = part + s * 262144;
  *(float4*)&po[row * 32 + c] = make_float4(acc[0], acc[1], acc[2], acc[3]);
  *(float4*)&po[(row + 1) * 32 + c] = make_float4(acc[4], acc[5], acc[6], acc[7]);
  if (tc == 0) {
    partS[s * 8192 + row] = sp0;
    partS[s * 8192 + row + 1] = sp1;
  }
}

// reduce split-K partials + bias; fuse diagonal chart/cn init.
__global__ __launch_bounds__(256) void k_node_reduce(
    const float* __restrict__ part, const float* __restrict__ partS,
    const float* __restrict__ bn, const float* __restrict__ bs,
    const float* __restrict__ D, float* __restrict__ node,
    float* __restrict__ chart, float* __restrict__ cn,
    float* __restrict__ span) {
  int t = threadIdx.x;
  int row = blockIdx.x * 8 + (t >> 5);
  int c = t & 31;
  float v = bn[c];
#pragma unroll
  for (int s = 0; s < 4; ++s) v += part[s * 262144 + row * 32 + c];
  node[row * 32 + c] = v;
  int l = (row >> 5) & 31, m = row & 31;
  if (l == m) {
    float ch = v + D[(row >> 5) * 32 + c];
    chart[row * 32 + c] = ch;
    cn[row * 32 + c] = ch + v;
  }
  if (c == 0) {
    float sp = bs[0];
#pragma unroll
    for (int s = 0; s < 4; ++s) sp += partS[s * 8192 + row];
    span[row] = sp;
  }
}

// one block per chart cell; reads cn (=chart+node), writes chart and cn.
// last stage also emits the logits.
__global__ __launch_bounds__(1024) void k_stage(
    const float* __restrict__ node, const float* __restrict__ span,
    const float* __restrict__ R, float* __restrict__ chart,
    float* __restrict__ cn, int i, int nT, int isLast,
    const int* __restrict__ sm, const float* __restrict__ rootm,
    float* __restrict__ out) {
  __shared__ float EL[31][32];
  __shared__ float ER[31][32];
  __shared__ float gam[32];
  __shared__ float S_lds[1024];
  __shared__ float vals[32];
  __shared__ float G_s;
  int tid = threadIdx.x;
  int cell = blockIdx.x;
  int b = cell / nT, t0 = cell - b * nT;
  int base = (b * 32 + t0) * 32;
  int j = tid >> 5, p = tid & 31;
  bool act = j < i;
  float left = 0.f, right = 0.f, beta = 0.f;
  if (act) {
    left = cn[(base + t0 + j) * 32 + p];
    right = cn[((b * 32 + t0 + j + 1) * 32 + (t0 + i)) * 32 + p];
    float alpha = left;
    beta = right;
#pragma unroll
    for (int m = 16; m >= 1; m >>= 1) {
      alpha = fmaxf(alpha, __shfl_xor(alpha, m, 32));
      beta = fmaxf(beta, __shfl_xor(beta, m, 32));
    }
    if (p == 0) gam[j] = alpha + beta;
  }
  __syncthreads();
  if (tid < 32) {
    float g = (tid < i) ? gam[tid] : -3.0e38f;
#pragma unroll
    for (int m = 16; m >= 1; m >>= 1) g = fmaxf(g, __shfl_xor(g, m, 32));
    if (tid == 0) G_s = g;
  }
  __syncthreads();
  float G = G_s;
  if (act) {
    EL[j][p] = __expf(left + beta - G);
    ER[j][p] = __expf(right - beta);
  }
  __syncthreads();
  {
    int pp = tid >> 5, qq = tid & 31;
    float S = 0.f;
    for (int jj = 0; jj < i; ++jj) S += EL[jj][pp] * ER[jj][qq];
    S_lds[tid] = S;
  }
  __syncthreads();
  {
    int a = tid >> 5, cc = tid & 31;
    const float* Ra = R + (a << 10);
    float pt = 0.f;
#pragma unroll
    for (int k = 0; k < 32; ++k) pt += Ra[(k << 5) + cc] * S_lds[(k << 5) + cc];
#pragma unroll
    for (int m = 16; m >= 1; m >>= 1) pt += __shfl_xor(pt, m, 32);
    if (cc == 0) {
      int oi = (base + t0 + i) * 32 + a;
      float nd = node[oi];
      float v = G + __logf(pt) + nd + span[base + t0 + i];
      chart[oi] = v;
      cn[oi] = v + nd;
      if (isLast) vals[a] = v;
    }
  }
  if (isLast) {
    __syncthreads();
    if (tid < 32) {
      int len = 0;
#pragma unroll
      for (int l = 0; l < 32; ++l) len += sm[b * 32 + l];
      float cv = (len == 32) ? vals[tid]
                             : chart[((b * 32) * 32 + (len - 1)) * 32 + tid];
      out[b * 32 + tid] = cv + (rootm[tid] - 1.0f) * 1e10f;
    }
  }
}

extern "C" void kernel_launch(void* const* d_in, const int* in_sizes, int n_in,
                              void* d_out, int out_size, void* d_ws, size_t ws_size,
                              hipStream_t stream) {
  const float* ph    = (const float*)d_in[0];
  const float* sh    = (const float*)d_in[1];
  const int*   sm    = (const int*)  d_in[2];
  const float* Wp    = (const float*)d_in[3];
  const float* bp    = (const float*)d_in[4];
  const float* Wn    = (const float*)d_in[5];
  const float* bn    = (const float*)d_in[6];
  const float* Ws    = (const float*)d_in[7];
  const float* bs    = (const float*)d_in[8];
  const float* rs    = (const float*)d_in[9];
  const float* pu    = (const float*)d_in[10];
  const float* rootm = (const float*)d_in[11];
  const float* pm    = (const float*)d_in[12];
  const float* rm    = (const float*)d_in[13];
  const float* pum   = (const float*)d_in[14];
  float* out = (float*)d_out;

  float* ws    = (float*)d_ws;
  float* node  = ws + NODE_OFF;
  float* chart = ws + CHART_OFF;
  float* cn    = ws + CN_OFF;
  float* span  = ws + SPAN_OFF;
  float* D     = ws + D_OFF;
  float* R     = ws + R_OFF;
  float* part  = ws + PART_OFF;
  float* partS = ws + PARTS_OFF;

  k_prep<<<384, 256, 0, stream>>>(sh, Wp, bp, pm, pu, pum, rs, rm, D, R);
  k_node_main<<<512, 256, 0, stream>>>(ph, Wn, Ws, part, partS);
  k_node_reduce<<<1024, 256, 0, stream>>>(part, partS, bn, bs, D, node, chart, cn, span);
  for (int i = 1; i < 32; ++i) {
    int nT = 32 - i;
    k_stage<<<8 * nT, 1024, 0, stream>>>(node, span, R, chart, cn, i, nT,
                                         (i == 31) ? 1 : 0, sm, rootm, out);
  }
}